// Round 2
// baseline (391.578 us; speedup 1.0000x reference)
//
#include <hip/hip_runtime.h>

typedef short s16x8 __attribute__((ext_vector_type(8)));
typedef float f32x4 __attribute__((ext_vector_type(4)));
typedef unsigned short u16x4v __attribute__((ext_vector_type(4)));

#define NSPLIT 4
#define NROWS 16384   // B*N
// Fixed softmax shift: scores s=q·k with q,k>=0 concentrate ~20±6 (max ~51).
// exp(s-44) can't overflow (needs s>132); underflow harmless. Ratios exact.
#define MSHIFT 44.0f
#define NCH (2048 / NSPLIT / 64)   // key chunks per split

__device__ __forceinline__ unsigned short f2bf(float f) {
  union { float fl; unsigned int i; } v; v.fl = f;
  unsigned int x = v.i;
  x += 0x7fffu + ((x >> 16) & 1u);   // round-to-nearest-even
  return (unsigned short)(x >> 16);
}
__device__ __forceinline__ s16x8 load8_bf16(const unsigned short* p) {
  return *(const s16x8*)p;
}
__device__ __forceinline__ s16x8 load8_f32(const float* p) {
  float4 a = *(const float4*)p;
  float4 b = *(const float4*)(p + 4);
  s16x8 r;
  r[0] = (short)f2bf(a.x); r[1] = (short)f2bf(a.y);
  r[2] = (short)f2bf(a.z); r[3] = (short)f2bf(a.w);
  r[4] = (short)f2bf(b.x); r[5] = (short)f2bf(b.y);
  r[6] = (short)f2bf(b.z); r[7] = (short)f2bf(b.w);
  return r;
}
// V^T key permutation within 32-blocks: position 32a+8c+4b+d holds key
// 32a+16b+4c+d — makes the P^T MFMA B-fragment equal each lane's own S^T
// C-layout registers (no P LDS round-trip). Survives contiguous LDS staging
// since chunks are 64-aligned. nn must be a multiple of 4.
__device__ __forceinline__ int vperm(int nn) {
  return (nn & ~31) | (((nn >> 2) & 3) << 3) | (((nn >> 4) & 1) << 2);
}

// Direct global->LDS 16B DMA (no VGPR round-trip).
__device__ __forceinline__ void gload16(const void* g, void* l) {
  __builtin_amdgcn_global_load_lds(
      (const __attribute__((address_space(1))) void*)g,
      (__attribute__((address_space(3))) void*)l, 16, 0, 0);
}

// ---------------------------------------------------------------------------
// ADJ -> bitmask pack, fully coalesced: lane l reads col l of a 64-col span,
// __ballot(v!=0) IS the mask word (bit l = key l). 256B/instr contiguous,
// near-zero VALU. Wave packs 4 rows; block of 4 waves packs 16 rows.
// ---------------------------------------------------------------------------
__device__ __forceinline__ void pack_adj_body(
    const float* __restrict__ ADJ, unsigned long long* __restrict__ MASK)
{
  const int t = threadIdx.x;
  const int w = t >> 6;
  const int lane = t & 63;
  const int row0 = blockIdx.x * 16 + w * 4;
#pragma unroll
  for (int rr = 0; rr < 4; ++rr) {
    const float* src = ADJ + (size_t)(row0 + rr) * 2048;
    unsigned long long* dst = MASK + (size_t)(row0 + rr) * 32;
#pragma unroll 8
    for (int p = 0; p < 32; ++p) {
      const float v = src[p * 64 + lane];
      const unsigned long long word = __ballot(v != 0.f);
      if (lane == 0) dst[p] = word;
    }
  }
}

// ---------------------------------------------------------------------------
// Layer-1 QKV GEMM, merged: one block computes Q,K,V for its 16 rows —
// X loaded/converted ONCE, reused for all three weight matrices.
// wave w covers cols [w*32,+32). V written transposed with vperm.
// ---------------------------------------------------------------------------
__device__ __forceinline__ void qkv_merged_body(
    const float* __restrict__ X,
    const float* __restrict__ Wq, const float* __restrict__ bq, unsigned short* __restrict__ oq,
    const float* __restrict__ Wk, const float* __restrict__ bk, unsigned short* __restrict__ ok,
    const float* __restrict__ Wv, const float* __restrict__ bv, unsigned short* __restrict__ ovt)
{
  const int t = threadIdx.x;
  const int w = t >> 6;
  const int lane = t & 63;
  const int l15 = lane & 15;
  const int quad = lane >> 4;
  const int mbase = blockIdx.x * 16;

  s16x8 a[4];
  const float* ar = X + (size_t)(mbase + l15) * 128;
#pragma unroll
  for (int ks = 0; ks < 4; ++ks) a[ks] = load8_f32(ar + ks * 32 + quad * 8);

  const float* Ws[3] = {Wq, Wk, Wv};
  const float* bs[3] = {bq, bk, bv};
  unsigned short* outs[3] = {oq, ok, ovt};

#pragma unroll
  for (int which = 0; which < 3; ++which) {
    const float* W = Ws[which];
    const float* bias = bs[which];
    unsigned short* out = outs[which];
#pragma unroll
    for (int nt = 0; nt < 2; ++nt) {
      const int n = (w * 2 + nt) * 16 + l15;
      f32x4 acc = {0.f, 0.f, 0.f, 0.f};
      const float* wr = W + (size_t)n * 128;
#pragma unroll
      for (int ks = 0; ks < 4; ++ks)
        acc = __builtin_amdgcn_mfma_f32_16x16x32_bf16(
            a[ks], load8_f32(wr + ks * 32 + quad * 8), acc, 0, 0, 0);
      const float bv_ = bias[n];
      if (which < 2) {
#pragma unroll
        for (int r = 0; r < 4; ++r)   // C layout: row=quad*4+r, col=n [m89]
          out[(size_t)(mbase + quad * 4 + r) * 128 + n] = f2bf(fmaxf(acc[r] + bv_, 0.f));
      } else {
        const int b  = mbase >> 11;
        const int nn = (mbase & 2047) + quad * 4;
        u16x4v pk;
#pragma unroll
        for (int r = 0; r < 4; ++r) pk[r] = f2bf(fmaxf(acc[r] + bv_, 0.f));
        *(u16x4v*)(out + (size_t)(b * 128 + n) * 2048 + vperm(nn)) = pk;
      }
    }
  }
}

__global__ __launch_bounds__(256) void qkv1_kernel(
    const float* __restrict__ x,
    const float* __restrict__ Wq, const float* __restrict__ bq, unsigned short* __restrict__ oq,
    const float* __restrict__ Wk, const float* __restrict__ bk, unsigned short* __restrict__ ok,
    const float* __restrict__ Wv, const float* __restrict__ bv, unsigned short* __restrict__ ovt,
    const float* __restrict__ adj, unsigned long long* __restrict__ mask)
{
  if (blockIdx.y == 0) qkv_merged_body(x, Wq, bq, oq, Wk, bk, ok, Wv, bv, ovt);
  else                 pack_adj_body(adj, mask);
}

// ---------------------------------------------------------------------------
// Split-K fixed-shift attention (mask-only now — ADJ pre-packed by qkv1):
//  * double-buffered LDS, staged via global_load_lds (16B), one barrier/chunk.
//  * linear LDS tiles with 16B-chunk XOR swizzle on source+read (rule 21).
//  * mask word prefetched one chunk ahead; s_setprio around MFMA clusters.
// S^T = K·Q^T (col=q); p stays in registers and IS the P^T B-fragment
// (vperm'd V^T). O^T = V^T·P^T; l via ones-MFMA. grid (128, NSPLIT).
// ---------------------------------------------------------------------------
__global__ __launch_bounds__(256, 2) void attn_kernel(
    const unsigned short* __restrict__ Q,
    const unsigned short* __restrict__ K,
    const unsigned short* __restrict__ VT,    // vperm'd layout
    const unsigned long long* __restrict__ MASK,
    float* __restrict__ pO, float* __restrict__ pl)
{
  __shared__ __align__(16) unsigned short kbuf[2][64][128];
  __shared__ __align__(16) unsigned short vbuf[2][128][64];

  const int t = threadIdx.x;
  const int w = t >> 6;
  const int lane = t & 63;
  const int l15 = lane & 15;
  const int quad = lane >> 4;
  const int x7 = l15 & 7;

  const int gq0 = blockIdx.x * 128;
  const int b   = gq0 >> 11;
  const int wq0 = (gq0 & 2047) + w * 32;
  const int kc0 = blockIdx.y * (2048 / NSPLIT);

  const unsigned short* Kb  = K  + (size_t)(b * 2048) * 128;
  const unsigned short* VTb = VT + (size_t)(b * 128) * 2048;
  const unsigned long long* Mb = MASK + (size_t)b * 2048 * 32;

  // staging thread-constants (16B slots; source chunk pre-swizzled so the
  // linear DMA write lands the swizzled layout)
  const int krow = t >> 4;                 // [0,16)
  const int kc16 = t & 15;
  const int kchunk = kc16 ^ (krow & 7);
  const int vrow = t >> 3;                 // [0,32)
  const int vc16 = t & 7;
  const int vchunk = vc16 ^ (vrow & 7);

  s16x8 qf[2][4];
#pragma unroll
  for (int mt = 0; mt < 2; ++mt) {
    const unsigned short* qrow = Q + (size_t)(gq0 + w * 32 + mt * 16 + l15) * 128;
#pragma unroll
    for (int ks = 0; ks < 4; ++ks) qf[mt][ks] = load8_bf16(qrow + ks * 32 + quad * 8);
  }

  s16x8 ones;
#pragma unroll
  for (int i = 0; i < 8; ++i) ones[i] = (short)0x3F80;   // bf16 1.0

  f32x4 accO[2][8];
  f32x4 accL[2];
#pragma unroll
  for (int mt = 0; mt < 2; ++mt) {
    accL[mt] = (f32x4){0.f, 0.f, 0.f, 0.f};
#pragma unroll
    for (int dt = 0; dt < 8; ++dt) accO[mt][dt] = (f32x4){0.f, 0.f, 0.f, 0.f};
  }

  // ---- prologue: DMA chunk 0 into buffer 0, load chunk-0 mask ----
#pragma unroll
  for (int i = 0; i < 4; ++i)
    gload16(Kb + (size_t)(kc0 + i * 16 + krow) * 128 + kchunk * 8,
            &kbuf[0][i * 16 + krow][kc16 * 8]);
#pragma unroll
  for (int i = 0; i < 4; ++i)
    gload16(VTb + (size_t)(i * 32 + vrow) * 2048 + kc0 + vchunk * 8,
            &vbuf[0][i * 32 + vrow][vc16 * 8]);

  unsigned long long mwc[2];
#pragma unroll
  for (int mt = 0; mt < 2; ++mt)
    mwc[mt] = Mb[(size_t)(wq0 + mt * 16 + l15) * 32 + (kc0 >> 6)];

  __syncthreads();   // drains the DMA (implicit vmcnt(0)) — buffer 0 ready

#pragma unroll 2
  for (int ci = 0; ci < NCH; ++ci) {
    const int kc = kc0 + ci * 64;
    unsigned short (*kb)[128] = kbuf[ci & 1];
    unsigned short (*vb)[64]  = vbuf[ci & 1];

    // 1. issue next-chunk DMA into the other buffer
    if (ci + 1 < NCH) {
      unsigned short (*kbn)[128] = kbuf[(ci + 1) & 1];
      unsigned short (*vbn)[64]  = vbuf[(ci + 1) & 1];
#pragma unroll
      for (int i = 0; i < 4; ++i)
        gload16(Kb + (size_t)(kc + 64 + i * 16 + krow) * 128 + kchunk * 8,
                &kbn[i * 16 + krow][kc16 * 8]);
#pragma unroll
      for (int i = 0; i < 4; ++i)
        gload16(VTb + (size_t)(i * 32 + vrow) * 2048 + (kc + 64) + vchunk * 8,
                &vbn[i * 32 + vrow][vc16 * 8]);
    }

    // 2. current mask -> kept, prefetch next mask
    unsigned long long kept[2];
    kept[0] = mwc[0];
    kept[1] = mwc[1];
    if (ci + 1 < NCH) {
#pragma unroll
      for (int mt = 0; mt < 2; ++mt)
        mwc[mt] = Mb[(size_t)(wq0 + mt * 16 + l15) * 32 + ((kc + 64) >> 6)];
    }

    // 3. S^T = K·Q^T : C rows = key = nt*16+quad*4+r, cols = q = l15
    f32x4 sv[2][4];
#pragma unroll
    for (int nt = 0; nt < 4; ++nt) {
      sv[0][nt] = (f32x4){0.f, 0.f, 0.f, 0.f};
      sv[1][nt] = (f32x4){0.f, 0.f, 0.f, 0.f};
    }
    __builtin_amdgcn_s_setprio(1);
#pragma unroll
    for (int nt = 0; nt < 4; ++nt)
#pragma unroll
      for (int ks = 0; ks < 4; ++ks) {
        s16x8 kf = *(const s16x8*)&kb[nt * 16 + l15][((ks * 4 + quad) ^ x7) * 8];
        sv[0][nt] = __builtin_amdgcn_mfma_f32_16x16x32_bf16(kf, qf[0][ks], sv[0][nt], 0, 0, 0);
        sv[1][nt] = __builtin_amdgcn_mfma_f32_16x16x32_bf16(kf, qf[1][ks], sv[1][nt], 0, 0, 0);
      }
    __builtin_amdgcn_s_setprio(0);

    // 4. p = kept ? exp(s-MSHIFT) : 0, packed straight into the P^T
    //    B-fragment pf[ks] = {p[2ks][0..3], p[2ks+1][0..3]}
    s16x8 pf[2][2];
#pragma unroll
    for (int mt = 0; mt < 2; ++mt) {
      const unsigned int bl = (unsigned int)(kept[mt] >> (quad * 4));        // nt 0,1
      const unsigned int bh = (unsigned int)(kept[mt] >> (quad * 4 + 32));   // nt 2,3
#pragma unroll
      for (int ks = 0; ks < 2; ++ks) {
        s16x8 v;
#pragma unroll
        for (int half = 0; half < 2; ++half) {
          const int nt = ks * 2 + half;
          const unsigned int bits = (nt < 2) ? bl : bh;
          const int sh = (nt & 1) * 16;
#pragma unroll
          for (int r = 0; r < 4; ++r) {
            const float e = __expf(sv[mt][nt][r] - MSHIFT);
            const bool keep = (bits >> (sh + r)) & 1u;
            v[half * 4 + r] = (short)f2bf(keep ? e : 0.f);
          }
        }
        pf[mt][ks] = v;
      }
    }

    __builtin_amdgcn_s_setprio(1);
    // 5. l += P·1 (A = ones: every D row = rowsum over this chunk's keys)
#pragma unroll
    for (int mt = 0; mt < 2; ++mt)
#pragma unroll
      for (int ks = 0; ks < 2; ++ks)
        accL[mt] = __builtin_amdgcn_mfma_f32_16x16x32_bf16(ones, pf[mt][ks], accL[mt], 0, 0, 0);

    // 6. O^T += V^T·P^T : vf from LDS (vperm'd layout baked in)
#pragma unroll
    for (int dt = 0; dt < 8; ++dt)
#pragma unroll
      for (int ks = 0; ks < 2; ++ks) {
        s16x8 vf = *(const s16x8*)&vb[dt * 16 + l15][((ks * 4 + quad) ^ x7) * 8];
        accO[0][dt] = __builtin_amdgcn_mfma_f32_16x16x32_bf16(vf, pf[0][ks], accO[0][dt], 0, 0, 0);
        accO[1][dt] = __builtin_amdgcn_mfma_f32_16x16x32_bf16(vf, pf[1][ks], accO[1][dt], 0, 0, 0);
      }
    __builtin_amdgcn_s_setprio(0);

    // single barrier per chunk: implicit vmcnt(0)+lgkmcnt(0) drain makes the
    // next-chunk DMA visible and finishes this chunk's LDS reads.
    __syncthreads();
  }

  // store raw partials; O^T C-layout: q=l15 (col), d=dt*16+quad*4+r (row)
  float* pOs = pO + (size_t)blockIdx.y * NROWS * 128;
#pragma unroll
  for (int mt = 0; mt < 2; ++mt) {
    const int qg = gq0 + w * 32 + mt * 16 + l15;
#pragma unroll
    for (int dt = 0; dt < 8; ++dt)
      *(f32x4*)(pOs + (size_t)qg * 128 + dt * 16 + quad * 4) = accO[mt][dt];
  }
  if (quad == 0) {
#pragma unroll
    for (int mt = 0; mt < 2; ++mt)
      pl[blockIdx.y * NROWS + gq0 + w * 32 + mt * 16 + l15] = accL[mt][0];
  }
}

// ---------------------------------------------------------------------------
// Split-combine for 64 rows: plain sums (fixed shift ⇒ equal weights),
// normalize, bf16 into At.
// ---------------------------------------------------------------------------
__device__ __forceinline__ void combine64(
    const float* __restrict__ pO, const float* __restrict__ pl, int grow0,
    unsigned short (*At)[136])
{
  const int t = threadIdx.x;
#pragma unroll
  for (int u = 0; u < 4; ++u) {
    const int unit = u * 256 + t;
    const int row = unit >> 4;
    const int col8 = (unit & 15) * 8;
    const int grow = grow0 + row;
    float lsum = 0.f;
#pragma unroll
    for (int s = 0; s < NSPLIT; ++s) lsum += pl[s * NROWS + grow];
    const float inv = (lsum > 0.f) ? 1.f / lsum : 0.f;
    float acc8[8];
#pragma unroll
    for (int i = 0; i < 8; ++i) acc8[i] = 0.f;
#pragma unroll
    for (int s = 0; s < NSPLIT; ++s) {
      const float* p = pO + (size_t)s * NROWS * 128 + (size_t)grow * 128 + col8;
      float4 x0 = *(const float4*)p;
      float4 x1 = *(const float4*)(p + 4);
      acc8[0] += x0.x; acc8[1] += x0.y; acc8[2] += x0.z; acc8[3] += x0.w;
      acc8[4] += x1.x; acc8[5] += x1.y; acc8[6] += x1.z; acc8[7] += x1.w;
    }
#pragma unroll
    for (int i = 0; i < 8; ++i) At[row][col8 + i] = f2bf(acc8[i] * inv);
  }
}

// ---------------------------------------------------------------------------
// Fused: combine(64 rows) -> f1 = At@Wo1^T+bo1 -> Q2/K2/V2 (V2 vperm'd).
// 64-row blocks amortize each weight fragment over 4 m-tiles. grid (256).
// ---------------------------------------------------------------------------
__global__ __launch_bounds__(256) void redqkv_kernel(
    const float* __restrict__ pO, const float* __restrict__ pl,
    const float* __restrict__ Wo, const float* __restrict__ bo,
    const float* __restrict__ Wq, const float* __restrict__ bq, unsigned short* __restrict__ oq,
    const float* __restrict__ Wk, const float* __restrict__ bk, unsigned short* __restrict__ ok,
    const float* __restrict__ Wv, const float* __restrict__ bv, unsigned short* __restrict__ ovt)
{
  __shared__ __align__(16) unsigned short At[64][136];
  __shared__ __align__(16) unsigned short Bt[64][136];
  const int t = threadIdx.x;
  const int grow0 = blockIdx.x * 64;

  combine64(pO, pl, grow0, At);
  __syncthreads();

  const int w = t >> 6;
  const int lane = t & 63;
  const int l15 = lane & 15;
  const int quad = lane >> 4;

  s16x8 af[4][4];
#pragma unroll
  for (int mt = 0; mt < 4; ++mt)
#pragma unroll
    for (int ks = 0; ks < 4; ++ks)
      af[mt][ks] = *(const s16x8*)&At[mt * 16 + l15][ks * 32 + quad * 8];

#pragma unroll
  for (int nt = 0; nt < 2; ++nt) {
    const int n = (w * 2 + nt) * 16 + l15;
    const float* wr = Wo + (size_t)n * 128;
    s16x8 wf[4];
#pragma unroll
    for (int ks = 0; ks < 4; ++ks) wf[ks] = load8_f32(wr + ks * 32 + quad * 8);
    f32x4 acc[4];
#pragma unroll
    for (int mt = 0; mt < 4; ++mt) acc[mt] = (f32x4){0.f, 0.f, 0.f, 0.f};
#pragma unroll
    for (int mt = 0; mt < 4; ++mt)
#pragma unroll
      for (int ks = 0; ks < 4; ++ks)
        acc[mt] = __builtin_amdgcn_mfma_f32_16x16x32_bf16(af[mt][ks], wf[ks], acc[mt], 0, 0, 0);
    const float bv_ = bo[n];
#pragma unroll
    for (int mt = 0; mt < 4; ++mt)
#pragma unroll
      for (int r = 0; r < 4; ++r)
        Bt[mt * 16 + quad * 4 + r][n] = f2bf(acc[mt][r] + bv_);
  }
  __syncthreads();

  s16x8 a2[4][4];
#pragma unroll
  for (int mt = 0; mt < 4; ++mt)
#pragma unroll
    for (int ks = 0; ks < 4; ++ks)
      a2[mt][ks] = *(const s16x8*)&Bt[mt * 16 + l15][ks * 32 + quad * 8];

#pragma unroll
  for (int which = 0; which < 3; ++which) {
    const float* W = (which == 0) ? Wq : (which == 1) ? Wk : Wv;
    const float* bb = (which == 0) ? bq : (which == 1) ? bk : bv;
    unsigned short* out = (which == 0) ? oq : (which == 1) ? ok : ovt;
#pragma unroll
    for (int nt = 0; nt < 2; ++nt) {
      const int n = (w * 2 + nt) * 16 + l15;
      const float* wr = W + (size_t)n * 128;
      s16x8 wf[4];
#pragma unroll
      for (int ks = 0; ks < 4; ++ks) wf[ks] = load8_f32(wr + ks * 32 + quad * 8);
      f32x4 acc[4];
#pragma unroll
      for (int mt = 0; mt < 4; ++mt) acc[mt] = (f32x4){0.f, 0.f, 0.f, 0.f};
#pragma unroll
      for (int mt = 0; mt < 4; ++mt)
#pragma unroll
        for (int ks = 0; ks < 4; ++ks)
          acc[mt] = __builtin_amdgcn_mfma_f32_16x16x32_bf16(a2[mt][ks], wf[ks], acc[mt], 0, 0, 0);
      const float bv_ = bb[n];
      if (which < 2) {
#pragma unroll
        for (int mt = 0; mt < 4; ++mt)
#pragma unroll
          for (int r = 0; r < 4; ++r)
            out[(size_t)(grow0 + mt * 16 + quad * 4 + r) * 128 + n] =
                f2bf(fmaxf(acc[mt][r] + bv_, 0.f));
      } else {
        const int b = grow0 >> 11;
#pragma unroll
        for (int mt = 0; mt < 4; ++mt) {
          const int nn = (grow0 & 2047) + mt * 16 + quad * 4;
          u16x4v pk;
#pragma unroll
          for (int r = 0; r < 4; ++r) pk[r] = f2bf(fmaxf(acc[mt][r] + bv_, 0.f));
          *(u16x4v*)(out + (size_t)(b * 128 + n) * 2048 + vperm(nn)) = pk;
        }
      }
    }
  }
}

// ---------------------------------------------------------------------------
// Fused: combine(64 rows) -> f2 = At@Wo2^T+bo2 -> out = f2@WfL^T + vae2@WfR^T
// + bf. grid (256).
// ---------------------------------------------------------------------------
__global__ __launch_bounds__(256) void redfinal_kernel(
    const float* __restrict__ pO, const float* __restrict__ pl,
    const float* __restrict__ Wo, const float* __restrict__ bo,
    const float* __restrict__ Wf, const float* __restrict__ bff,
    const float* __restrict__ vae2, float* __restrict__ out)
{
  __shared__ __align__(16) unsigned short At[64][136];
  __shared__ __align__(16) unsigned short Bt[64][136];
  const int t = threadIdx.x;
  const int grow0 = blockIdx.x * 64;

  combine64(pO, pl, grow0, At);
  __syncthreads();

  const int w = t >> 6;
  const int lane = t & 63;
  const int l15 = lane & 15;
  const int quad = lane >> 4;

  s16x8 af[4][4];
#pragma unroll
  for (int mt = 0; mt < 4; ++mt)
#pragma unroll
    for (int ks = 0; ks < 4; ++ks)
      af[mt][ks] = *(const s16x8*)&At[mt * 16 + l15][ks * 32 + quad * 8];

#pragma unroll
  for (int nt = 0; nt < 2; ++nt) {
    const int n = (w * 2 + nt) * 16 + l15;
    const float* wr = Wo + (size_t)n * 128;
    s16x8 wf[4];
#pragma unroll
    for (int ks = 0; ks < 4; ++ks) wf[ks] = load8_f32(wr + ks * 32 + quad * 8);
    f32x4 acc[4];
#pragma unroll
    for (int mt = 0; mt < 4; ++mt) acc[mt] = (f32x4){0.f, 0.f, 0.f, 0.f};
#pragma unroll
    for (int mt = 0; mt < 4; ++mt)
#pragma unroll
      for (int ks = 0; ks < 4; ++ks)
        acc[mt] = __builtin_amdgcn_mfma_f32_16x16x32_bf16(af[mt][ks], wf[ks], acc[mt], 0, 0, 0);
    const float bv_ = bo[n];
#pragma unroll
    for (int mt = 0; mt < 4; ++mt)
#pragma unroll
      for (int r = 0; r < 4; ++r)
        Bt[mt * 16 + quad * 4 + r][n] = f2bf(acc[mt][r] + bv_);
  }
  __syncthreads();

  s16x8 a1[4][4], a2[4][4];
#pragma unroll
  for (int mt = 0; mt < 4; ++mt) {
#pragma unroll
    for (int ks = 0; ks < 4; ++ks)
      a1[mt][ks] = *(const s16x8*)&Bt[mt * 16 + l15][ks * 32 + quad * 8];
    const float* vrow = vae2 + (size_t)(grow0 + mt * 16 + l15) * 128;
#pragma unroll
    for (int ks = 0; ks < 4; ++ks) a2[mt][ks] = load8_f32(vrow + ks * 32 + quad * 8);
  }

#pragma unroll
  for (int nt = 0; nt < 2; ++nt) {
    const int n = (w * 2 + nt) * 16 + l15;
    const float* wr = Wf + (size_t)n * 256;
    s16x8 wfl[4], wfr[4];
#pragma unroll
    for (int ks = 0; ks < 4; ++ks) {
      wfl[ks] = load8_f32(wr + ks * 32 + quad * 8);
      wfr[ks] = load8_f32(wr + 128 + ks * 32 + quad * 8);
    }
    f32x4 acc[4];
#pragma unroll
    for (int mt = 0; mt < 4; ++mt) acc[mt] = (f32x4){0.f, 0.f, 0.f, 0.f};
#pragma unroll
    for (int mt = 0; mt < 4; ++mt) {
#pragma unroll
      for (int ks = 0; ks < 4; ++ks)
        acc[mt] = __builtin_amdgcn_mfma_f32_16x16x32_bf16(a1[mt][ks], wfl[ks], acc[mt], 0, 0, 0);
#pragma unroll
      for (int ks = 0; ks < 4; ++ks)
        acc[mt] = __builtin_amdgcn_mfma_f32_16x16x32_bf16(a2[mt][ks], wfr[ks], acc[mt], 0, 0, 0);
    }
    const float bv_ = bff[n];
#pragma unroll
    for (int mt = 0; mt < 4; ++mt)
#pragma unroll
      for (int r = 0; r < 4; ++r)
        out[(size_t)(grow0 + mt * 16 + quad * 4 + r) * 128 + n] = acc[mt][r] + bv_;
  }
}

extern "C" void kernel_launch(void* const* d_in, const int* in_sizes, int n_in,
                              void* d_out, int out_size, void* d_ws, size_t ws_size,
                              hipStream_t stream)
{
  const float* h    = (const float*)d_in[0];
  const float* adj  = (const float*)d_in[1];
  const float* vae2 = (const float*)d_in[2];
  const float* Wv1  = (const float*)d_in[3];
  const float* bv1  = (const float*)d_in[4];
  const float* Wk1  = (const float*)d_in[5];
  const float* bk1  = (const float*)d_in[6];
  const float* Wq1  = (const float*)d_in[7];
  const float* bq1  = (const float*)d_in[8];
  const float* Wo1  = (const float*)d_in[9];
  const float* bo1  = (const float*)d_in[10];
  const float* Wv2  = (const float*)d_in[11];
  const float* bv2  = (const float*)d_in[12];
  const float* Wk2  = (const float*)d_in[13];
  const float* bk2  = (const float*)d_in[14];
  const float* Wq2  = (const float*)d_in[15];
  const float* bq2  = (const float*)d_in[16];
  const float* Wo2  = (const float*)d_in[17];
  const float* bo2  = (const float*)d_in[18];
  const float* Wf   = (const float*)d_in[19];
  const float* bff  = (const float*)d_in[20];

  char* wsb = (char*)d_ws;
  const size_t MB = 1u << 20;
  unsigned short* s_q  = (unsigned short*)(wsb + 0 * MB);
  unsigned short* s_k  = (unsigned short*)(wsb + 4 * MB);
  unsigned short* s_vt = (unsigned short*)(wsb + 8 * MB);
  unsigned long long* maskp = (unsigned long long*)(wsb + 12 * MB);  // 4 MB
  float* pO = (float*)(wsb + 16 * MB);                               // 32 MB
  float* pl = (float*)(wsb + 48 * MB);                               // 256 KB

  qkv1_kernel<<<dim3(1024, 2), dim3(256), 0, stream>>>(
      h, Wq1, bq1, s_q, Wk1, bk1, s_k, Wv1, bv1, s_vt, adj, maskp);
  attn_kernel<<<dim3(128, NSPLIT), dim3(256), 0, stream>>>(
      s_q, s_k, s_vt, maskp, pO, pl);
  redqkv_kernel<<<dim3(256), dim3(256), 0, stream>>>(
      pO, pl, Wo1, bo1, Wq2, bq2, s_q, Wk2, bk2, s_k, Wv2, bv2, s_vt);
  attn_kernel<<<dim3(128, NSPLIT), dim3(256), 0, stream>>>(
      s_q, s_k, s_vt, maskp, pO, pl);
  redfinal_kernel<<<dim3(256), dim3(256), 0, stream>>>(
      pO, pl, Wo2, bo2, Wf, bff, vae2, (float*)d_out);
}

// Round 3
// 351.890 us; speedup vs baseline: 1.1128x; 1.1128x over previous
//
#include <hip/hip_runtime.h>

typedef short s16x8 __attribute__((ext_vector_type(8)));
typedef float f32x4 __attribute__((ext_vector_type(4)));
typedef unsigned short u16x4v __attribute__((ext_vector_type(4)));

#define NSPLIT 4
#define NROWS 16384   // B*N
// Fixed softmax shift: scores s=q·k with q,k>=0 concentrate ~20±6 (max ~51).
// exp(s-44) can't overflow (needs s>132); underflow harmless. Ratios exact.
#define MSHIFT 44.0f
#define NCH (2048 / NSPLIT / 64)   // key chunks per split

__device__ __forceinline__ unsigned short f2bf(float f) {
  union { float fl; unsigned int i; } v; v.fl = f;
  unsigned int x = v.i;
  x += 0x7fffu + ((x >> 16) & 1u);   // round-to-nearest-even
  return (unsigned short)(x >> 16);
}
__device__ __forceinline__ s16x8 load8_bf16(const unsigned short* p) {
  return *(const s16x8*)p;
}
__device__ __forceinline__ s16x8 load8_f32(const float* p) {
  float4 a = *(const float4*)p;
  float4 b = *(const float4*)(p + 4);
  s16x8 r;
  r[0] = (short)f2bf(a.x); r[1] = (short)f2bf(a.y);
  r[2] = (short)f2bf(a.z); r[3] = (short)f2bf(a.w);
  r[4] = (short)f2bf(b.x); r[5] = (short)f2bf(b.y);
  r[6] = (short)f2bf(b.z); r[7] = (short)f2bf(b.w);
  return r;
}
// V^T key permutation within 32-blocks: position 32a+8c+4b+d holds key
// 32a+16b+4c+d — makes the P^T MFMA B-fragment equal each lane's own S^T
// C-layout registers (no P LDS round-trip). Survives contiguous LDS staging
// since chunks are 64-aligned. nn must be a multiple of 4.
__device__ __forceinline__ int vperm(int nn) {
  return (nn & ~31) | (((nn >> 2) & 3) << 3) | (((nn >> 4) & 1) << 2);
}

// Direct global->LDS 16B DMA (no VGPR round-trip).
__device__ __forceinline__ void gload16(const void* g, void* l) {
  __builtin_amdgcn_global_load_lds(
      (const __attribute__((address_space(1))) void*)g,
      (__attribute__((address_space(3))) void*)l, 16, 0, 0);
}

// ---------------------------------------------------------------------------
// ADJ -> bitmask pack, latency-tolerant form. Wave packs 2 rows:
//  * issue ALL 64 dword loads into registers first (one latency exposure),
//  * then 64 ballots; word p is collected into lane p via predicated move
//    (no per-word divergent store),
//  * one coalesced 256B store per row (lanes 0..31 store their u64).
// 2048 pack blocks (grid y in {1,2}) x 8 rows = 16384 rows.
// ---------------------------------------------------------------------------
__device__ __forceinline__ void pack_adj_body(
    const float* __restrict__ ADJ, unsigned long long* __restrict__ MASK)
{
  const int t = threadIdx.x;
  const int w = t >> 6;
  const int lane = t & 63;
  const int pid = (blockIdx.y - 1) * 1024 + blockIdx.x;
  const int row0 = pid * 8 + w * 2;

  const float* s0 = ADJ + (size_t)row0 * 2048;
  const float* s1 = s0 + 2048;

  float va[32], vb[32];
#pragma unroll
  for (int p = 0; p < 32; ++p) va[p] = s0[p * 64 + lane];
#pragma unroll
  for (int p = 0; p < 32; ++p) vb[p] = s1[p * 64 + lane];

  unsigned long long wa = 0ull, wb = 0ull;
#pragma unroll
  for (int p = 0; p < 32; ++p) {
    const unsigned long long m = __ballot(va[p] != 0.f);
    wa = (lane == p) ? m : wa;
  }
#pragma unroll
  for (int p = 0; p < 32; ++p) {
    const unsigned long long m = __ballot(vb[p] != 0.f);
    wb = (lane == p) ? m : wb;
  }

  if (lane < 32) {
    MASK[(size_t)row0 * 32 + lane] = wa;
    MASK[(size_t)(row0 + 1) * 32 + lane] = wb;
  }
}

// ---------------------------------------------------------------------------
// Layer-1 QKV GEMM, merged: one block computes Q,K,V for its 16 rows —
// X loaded/converted ONCE, reused for all three weight matrices.
// wave w covers cols [w*32,+32). V written transposed with vperm.
// ---------------------------------------------------------------------------
__device__ __forceinline__ void qkv_merged_body(
    const float* __restrict__ X,
    const float* __restrict__ Wq, const float* __restrict__ bq, unsigned short* __restrict__ oq,
    const float* __restrict__ Wk, const float* __restrict__ bk, unsigned short* __restrict__ ok,
    const float* __restrict__ Wv, const float* __restrict__ bv, unsigned short* __restrict__ ovt)
{
  const int t = threadIdx.x;
  const int w = t >> 6;
  const int lane = t & 63;
  const int l15 = lane & 15;
  const int quad = lane >> 4;
  const int mbase = blockIdx.x * 16;

  s16x8 a[4];
  const float* ar = X + (size_t)(mbase + l15) * 128;
#pragma unroll
  for (int ks = 0; ks < 4; ++ks) a[ks] = load8_f32(ar + ks * 32 + quad * 8);

  const float* Ws[3] = {Wq, Wk, Wv};
  const float* bs[3] = {bq, bk, bv};
  unsigned short* outs[3] = {oq, ok, ovt};

#pragma unroll
  for (int which = 0; which < 3; ++which) {
    const float* W = Ws[which];
    const float* bias = bs[which];
    unsigned short* out = outs[which];
#pragma unroll
    for (int nt = 0; nt < 2; ++nt) {
      const int n = (w * 2 + nt) * 16 + l15;
      f32x4 acc = {0.f, 0.f, 0.f, 0.f};
      const float* wr = W + (size_t)n * 128;
#pragma unroll
      for (int ks = 0; ks < 4; ++ks)
        acc = __builtin_amdgcn_mfma_f32_16x16x32_bf16(
            a[ks], load8_f32(wr + ks * 32 + quad * 8), acc, 0, 0, 0);
      const float bv_ = bias[n];
      if (which < 2) {
#pragma unroll
        for (int r = 0; r < 4; ++r)   // C layout: row=quad*4+r, col=n [m89]
          out[(size_t)(mbase + quad * 4 + r) * 128 + n] = f2bf(fmaxf(acc[r] + bv_, 0.f));
      } else {
        const int b  = mbase >> 11;
        const int nn = (mbase & 2047) + quad * 4;
        u16x4v pk;
#pragma unroll
        for (int r = 0; r < 4; ++r) pk[r] = f2bf(fmaxf(acc[r] + bv_, 0.f));
        *(u16x4v*)(out + (size_t)(b * 128 + n) * 2048 + vperm(nn)) = pk;
      }
    }
  }
}

__global__ __launch_bounds__(256) void qkv1_kernel(
    const float* __restrict__ x,
    const float* __restrict__ Wq, const float* __restrict__ bq, unsigned short* __restrict__ oq,
    const float* __restrict__ Wk, const float* __restrict__ bk, unsigned short* __restrict__ ok,
    const float* __restrict__ Wv, const float* __restrict__ bv, unsigned short* __restrict__ ovt,
    const float* __restrict__ adj, unsigned long long* __restrict__ mask)
{
  if (blockIdx.y == 0) qkv_merged_body(x, Wq, bq, oq, Wk, bk, ok, Wv, bv, ovt);
  else                 pack_adj_body(adj, mask);
}

// ---------------------------------------------------------------------------
// Split-K fixed-shift attention (mask-only — ADJ pre-packed by qkv1):
//  * double-buffered LDS, staged via global_load_lds (16B), one barrier/chunk.
//  * linear LDS tiles with 16B-chunk XOR swizzle on source+read (rule 21).
//  * mask word prefetched one chunk ahead; s_setprio around MFMA clusters.
// S^T = K·Q^T (col=q); p stays in registers and IS the P^T B-fragment
// (vperm'd V^T). O^T = V^T·P^T; l via ones-MFMA. grid (128, NSPLIT).
// ---------------------------------------------------------------------------
__global__ __launch_bounds__(256, 2) void attn_kernel(
    const unsigned short* __restrict__ Q,
    const unsigned short* __restrict__ K,
    const unsigned short* __restrict__ VT,    // vperm'd layout
    const unsigned long long* __restrict__ MASK,
    float* __restrict__ pO, float* __restrict__ pl)
{
  __shared__ __align__(16) unsigned short kbuf[2][64][128];
  __shared__ __align__(16) unsigned short vbuf[2][128][64];

  const int t = threadIdx.x;
  const int w = t >> 6;
  const int lane = t & 63;
  const int l15 = lane & 15;
  const int quad = lane >> 4;
  const int x7 = l15 & 7;

  const int gq0 = blockIdx.x * 128;
  const int b   = gq0 >> 11;
  const int wq0 = (gq0 & 2047) + w * 32;
  const int kc0 = blockIdx.y * (2048 / NSPLIT);

  const unsigned short* Kb  = K  + (size_t)(b * 2048) * 128;
  const unsigned short* VTb = VT + (size_t)(b * 128) * 2048;
  const unsigned long long* Mb = MASK + (size_t)b * 2048 * 32;

  // staging thread-constants (16B slots; source chunk pre-swizzled so the
  // linear DMA write lands the swizzled layout)
  const int krow = t >> 4;                 // [0,16)
  const int kc16 = t & 15;
  const int kchunk = kc16 ^ (krow & 7);
  const int vrow = t >> 3;                 // [0,32)
  const int vc16 = t & 7;
  const int vchunk = vc16 ^ (vrow & 7);

  s16x8 qf[2][4];
#pragma unroll
  for (int mt = 0; mt < 2; ++mt) {
    const unsigned short* qrow = Q + (size_t)(gq0 + w * 32 + mt * 16 + l15) * 128;
#pragma unroll
    for (int ks = 0; ks < 4; ++ks) qf[mt][ks] = load8_bf16(qrow + ks * 32 + quad * 8);
  }

  s16x8 ones;
#pragma unroll
  for (int i = 0; i < 8; ++i) ones[i] = (short)0x3F80;   // bf16 1.0

  f32x4 accO[2][8];
  f32x4 accL[2];
#pragma unroll
  for (int mt = 0; mt < 2; ++mt) {
    accL[mt] = (f32x4){0.f, 0.f, 0.f, 0.f};
#pragma unroll
    for (int dt = 0; dt < 8; ++dt) accO[mt][dt] = (f32x4){0.f, 0.f, 0.f, 0.f};
  }

  // ---- prologue: DMA chunk 0 into buffer 0, load chunk-0 mask ----
#pragma unroll
  for (int i = 0; i < 4; ++i)
    gload16(Kb + (size_t)(kc0 + i * 16 + krow) * 128 + kchunk * 8,
            &kbuf[0][i * 16 + krow][kc16 * 8]);
#pragma unroll
  for (int i = 0; i < 4; ++i)
    gload16(VTb + (size_t)(i * 32 + vrow) * 2048 + kc0 + vchunk * 8,
            &vbuf[0][i * 32 + vrow][vc16 * 8]);

  unsigned long long mwc[2];
#pragma unroll
  for (int mt = 0; mt < 2; ++mt)
    mwc[mt] = Mb[(size_t)(wq0 + mt * 16 + l15) * 32 + (kc0 >> 6)];

  __syncthreads();   // drains the DMA (implicit vmcnt(0)) — buffer 0 ready

#pragma unroll 2
  for (int ci = 0; ci < NCH; ++ci) {
    const int kc = kc0 + ci * 64;
    unsigned short (*kb)[128] = kbuf[ci & 1];
    unsigned short (*vb)[64]  = vbuf[ci & 1];

    // 1. issue next-chunk DMA into the other buffer
    if (ci + 1 < NCH) {
      unsigned short (*kbn)[128] = kbuf[(ci + 1) & 1];
      unsigned short (*vbn)[64]  = vbuf[(ci + 1) & 1];
#pragma unroll
      for (int i = 0; i < 4; ++i)
        gload16(Kb + (size_t)(kc + 64 + i * 16 + krow) * 128 + kchunk * 8,
                &kbn[i * 16 + krow][kc16 * 8]);
#pragma unroll
      for (int i = 0; i < 4; ++i)
        gload16(VTb + (size_t)(i * 32 + vrow) * 2048 + (kc + 64) + vchunk * 8,
                &vbn[i * 32 + vrow][vc16 * 8]);
    }

    // 2. current mask -> kept, prefetch next mask
    unsigned long long kept[2];
    kept[0] = mwc[0];
    kept[1] = mwc[1];
    if (ci + 1 < NCH) {
#pragma unroll
      for (int mt = 0; mt < 2; ++mt)
        mwc[mt] = Mb[(size_t)(wq0 + mt * 16 + l15) * 32 + ((kc + 64) >> 6)];
    }

    // 3. S^T = K·Q^T : C rows = key = nt*16+quad*4+r, cols = q = l15
    f32x4 sv[2][4];
#pragma unroll
    for (int nt = 0; nt < 4; ++nt) {
      sv[0][nt] = (f32x4){0.f, 0.f, 0.f, 0.f};
      sv[1][nt] = (f32x4){0.f, 0.f, 0.f, 0.f};
    }
    __builtin_amdgcn_s_setprio(1);
#pragma unroll
    for (int nt = 0; nt < 4; ++nt)
#pragma unroll
      for (int ks = 0; ks < 4; ++ks) {
        s16x8 kf = *(const s16x8*)&kb[nt * 16 + l15][((ks * 4 + quad) ^ x7) * 8];
        sv[0][nt] = __builtin_amdgcn_mfma_f32_16x16x32_bf16(kf, qf[0][ks], sv[0][nt], 0, 0, 0);
        sv[1][nt] = __builtin_amdgcn_mfma_f32_16x16x32_bf16(kf, qf[1][ks], sv[1][nt], 0, 0, 0);
      }
    __builtin_amdgcn_s_setprio(0);

    // 4. p = kept ? exp(s-MSHIFT) : 0, packed straight into the P^T
    //    B-fragment pf[ks] = {p[2ks][0..3], p[2ks+1][0..3]}
    s16x8 pf[2][2];
#pragma unroll
    for (int mt = 0; mt < 2; ++mt) {
      const unsigned int bl = (unsigned int)(kept[mt] >> (quad * 4));        // nt 0,1
      const unsigned int bh = (unsigned int)(kept[mt] >> (quad * 4 + 32));   // nt 2,3
#pragma unroll
      for (int ks = 0; ks < 2; ++ks) {
        s16x8 v;
#pragma unroll
        for (int half = 0; half < 2; ++half) {
          const int nt = ks * 2 + half;
          const unsigned int bits = (nt < 2) ? bl : bh;
          const int sh = (nt & 1) * 16;
#pragma unroll
          for (int r = 0; r < 4; ++r) {
            const float e = __expf(sv[mt][nt][r] - MSHIFT);
            const bool keep = (bits >> (sh + r)) & 1u;
            v[half * 4 + r] = (short)f2bf(keep ? e : 0.f);
          }
        }
        pf[mt][ks] = v;
      }
    }

    __builtin_amdgcn_s_setprio(1);
    // 5. l += P·1 (A = ones: every D row = rowsum over this chunk's keys)
#pragma unroll
    for (int mt = 0; mt < 2; ++mt)
#pragma unroll
      for (int ks = 0; ks < 2; ++ks)
        accL[mt] = __builtin_amdgcn_mfma_f32_16x16x32_bf16(ones, pf[mt][ks], accL[mt], 0, 0, 0);

    // 6. O^T += V^T·P^T : vf from LDS (vperm'd layout baked in)
#pragma unroll
    for (int dt = 0; dt < 8; ++dt)
#pragma unroll
      for (int ks = 0; ks < 2; ++ks) {
        s16x8 vf = *(const s16x8*)&vb[dt * 16 + l15][((ks * 4 + quad) ^ x7) * 8];
        accO[0][dt] = __builtin_amdgcn_mfma_f32_16x16x32_bf16(vf, pf[0][ks], accO[0][dt], 0, 0, 0);
        accO[1][dt] = __builtin_amdgcn_mfma_f32_16x16x32_bf16(vf, pf[1][ks], accO[1][dt], 0, 0, 0);
      }
    __builtin_amdgcn_s_setprio(0);

    // single barrier per chunk: implicit vmcnt(0)+lgkmcnt(0) drain makes the
    // next-chunk DMA visible and finishes this chunk's LDS reads.
    __syncthreads();
  }

  // store raw partials; O^T C-layout: q=l15 (col), d=dt*16+quad*4+r (row)
  float* pOs = pO + (size_t)blockIdx.y * NROWS * 128;
#pragma unroll
  for (int mt = 0; mt < 2; ++mt) {
    const int qg = gq0 + w * 32 + mt * 16 + l15;
#pragma unroll
    for (int dt = 0; dt < 8; ++dt)
      *(f32x4*)(pOs + (size_t)qg * 128 + dt * 16 + quad * 4) = accO[mt][dt];
  }
  if (quad == 0) {
#pragma unroll
    for (int mt = 0; mt < 2; ++mt)
      pl[blockIdx.y * NROWS + gq0 + w * 32 + mt * 16 + l15] = accL[mt][0];
  }
}

// ---------------------------------------------------------------------------
// Split-combine for 64 rows: plain sums (fixed shift ⇒ equal weights),
// normalize, bf16 into At.
// ---------------------------------------------------------------------------
__device__ __forceinline__ void combine64(
    const float* __restrict__ pO, const float* __restrict__ pl, int grow0,
    unsigned short (*At)[136])
{
  const int t = threadIdx.x;
#pragma unroll
  for (int u = 0; u < 4; ++u) {
    const int unit = u * 256 + t;
    const int row = unit >> 4;
    const int col8 = (unit & 15) * 8;
    const int grow = grow0 + row;
    float lsum = 0.f;
#pragma unroll
    for (int s = 0; s < NSPLIT; ++s) lsum += pl[s * NROWS + grow];
    const float inv = (lsum > 0.f) ? 1.f / lsum : 0.f;
    float acc8[8];
#pragma unroll
    for (int i = 0; i < 8; ++i) acc8[i] = 0.f;
#pragma unroll
    for (int s = 0; s < NSPLIT; ++s) {
      const float* p = pO + (size_t)s * NROWS * 128 + (size_t)grow * 128 + col8;
      float4 x0 = *(const float4*)p;
      float4 x1 = *(const float4*)(p + 4);
      acc8[0] += x0.x; acc8[1] += x0.y; acc8[2] += x0.z; acc8[3] += x0.w;
      acc8[4] += x1.x; acc8[5] += x1.y; acc8[6] += x1.z; acc8[7] += x1.w;
    }
#pragma unroll
    for (int i = 0; i < 8; ++i) At[row][col8 + i] = f2bf(acc8[i] * inv);
  }
}

// ---------------------------------------------------------------------------
// Fused: combine(64 rows) -> f1 = At@Wo1^T+bo1 -> Q2/K2/V2 (V2 vperm'd).
// 64-row blocks amortize each weight fragment over 4 m-tiles. grid (256).
// ---------------------------------------------------------------------------
__global__ __launch_bounds__(256) void redqkv_kernel(
    const float* __restrict__ pO, const float* __restrict__ pl,
    const float* __restrict__ Wo, const float* __restrict__ bo,
    const float* __restrict__ Wq, const float* __restrict__ bq, unsigned short* __restrict__ oq,
    const float* __restrict__ Wk, const float* __restrict__ bk, unsigned short* __restrict__ ok,
    const float* __restrict__ Wv, const float* __restrict__ bv, unsigned short* __restrict__ ovt)
{
  __shared__ __align__(16) unsigned short At[64][136];
  __shared__ __align__(16) unsigned short Bt[64][136];
  const int t = threadIdx.x;
  const int grow0 = blockIdx.x * 64;

  combine64(pO, pl, grow0, At);
  __syncthreads();

  const int w = t >> 6;
  const int lane = t & 63;
  const int l15 = lane & 15;
  const int quad = lane >> 4;

  s16x8 af[4][4];
#pragma unroll
  for (int mt = 0; mt < 4; ++mt)
#pragma unroll
    for (int ks = 0; ks < 4; ++ks)
      af[mt][ks] = *(const s16x8*)&At[mt * 16 + l15][ks * 32 + quad * 8];

#pragma unroll
  for (int nt = 0; nt < 2; ++nt) {
    const int n = (w * 2 + nt) * 16 + l15;
    const float* wr = Wo + (size_t)n * 128;
    s16x8 wf[4];
#pragma unroll
    for (int ks = 0; ks < 4; ++ks) wf[ks] = load8_f32(wr + ks * 32 + quad * 8);
    f32x4 acc[4];
#pragma unroll
    for (int mt = 0; mt < 4; ++mt) acc[mt] = (f32x4){0.f, 0.f, 0.f, 0.f};
#pragma unroll
    for (int mt = 0; mt < 4; ++mt)
#pragma unroll
      for (int ks = 0; ks < 4; ++ks)
        acc[mt] = __builtin_amdgcn_mfma_f32_16x16x32_bf16(af[mt][ks], wf[ks], acc[mt], 0, 0, 0);
    const float bv_ = bo[n];
#pragma unroll
    for (int mt = 0; mt < 4; ++mt)
#pragma unroll
      for (int r = 0; r < 4; ++r)
        Bt[mt * 16 + quad * 4 + r][n] = f2bf(acc[mt][r] + bv_);
  }
  __syncthreads();

  s16x8 a2[4][4];
#pragma unroll
  for (int mt = 0; mt < 4; ++mt)
#pragma unroll
    for (int ks = 0; ks < 4; ++ks)
      a2[mt][ks] = *(const s16x8*)&Bt[mt * 16 + l15][ks * 32 + quad * 8];

#pragma unroll
  for (int which = 0; which < 3; ++which) {
    const float* W = (which == 0) ? Wq : (which == 1) ? Wk : Wv;
    const float* bb = (which == 0) ? bq : (which == 1) ? bk : bv;
    unsigned short* out = (which == 0) ? oq : (which == 1) ? ok : ovt;
#pragma unroll
    for (int nt = 0; nt < 2; ++nt) {
      const int n = (w * 2 + nt) * 16 + l15;
      const float* wr = W + (size_t)n * 128;
      s16x8 wf[4];
#pragma unroll
      for (int ks = 0; ks < 4; ++ks) wf[ks] = load8_f32(wr + ks * 32 + quad * 8);
      f32x4 acc[4];
#pragma unroll
      for (int mt = 0; mt < 4; ++mt) acc[mt] = (f32x4){0.f, 0.f, 0.f, 0.f};
#pragma unroll
      for (int mt = 0; mt < 4; ++mt)
#pragma unroll
        for (int ks = 0; ks < 4; ++ks)
          acc[mt] = __builtin_amdgcn_mfma_f32_16x16x32_bf16(a2[mt][ks], wf[ks], acc[mt], 0, 0, 0);
      const float bv_ = bb[n];
      if (which < 2) {
#pragma unroll
        for (int mt = 0; mt < 4; ++mt)
#pragma unroll
          for (int r = 0; r < 4; ++r)
            out[(size_t)(grow0 + mt * 16 + quad * 4 + r) * 128 + n] =
                f2bf(fmaxf(acc[mt][r] + bv_, 0.f));
      } else {
        const int b = grow0 >> 11;
#pragma unroll
        for (int mt = 0; mt < 4; ++mt) {
          const int nn = (grow0 & 2047) + mt * 16 + quad * 4;
          u16x4v pk;
#pragma unroll
          for (int r = 0; r < 4; ++r) pk[r] = f2bf(fmaxf(acc[mt][r] + bv_, 0.f));
          *(u16x4v*)(out + (size_t)(b * 128 + n) * 2048 + vperm(nn)) = pk;
        }
      }
    }
  }
}

// ---------------------------------------------------------------------------
// Fused: combine(64 rows) -> f2 = At@Wo2^T+bo2 -> out = f2@WfL^T + vae2@WfR^T
// + bf. grid (256).
// ---------------------------------------------------------------------------
__global__ __launch_bounds__(256) void redfinal_kernel(
    const float* __restrict__ pO, const float* __restrict__ pl,
    const float* __restrict__ Wo, const float* __restrict__ bo,
    const float* __restrict__ Wf, const float* __restrict__ bff,
    const float* __restrict__ vae2, float* __restrict__ out)
{
  __shared__ __align__(16) unsigned short At[64][136];
  __shared__ __align__(16) unsigned short Bt[64][136];
  const int t = threadIdx.x;
  const int grow0 = blockIdx.x * 64;

  combine64(pO, pl, grow0, At);
  __syncthreads();

  const int w = t >> 6;
  const int lane = t & 63;
  const int l15 = lane & 15;
  const int quad = lane >> 4;

  s16x8 af[4][4];
#pragma unroll
  for (int mt = 0; mt < 4; ++mt)
#pragma unroll
    for (int ks = 0; ks < 4; ++ks)
      af[mt][ks] = *(const s16x8*)&At[mt * 16 + l15][ks * 32 + quad * 8];

#pragma unroll
  for (int nt = 0; nt < 2; ++nt) {
    const int n = (w * 2 + nt) * 16 + l15;
    const float* wr = Wo + (size_t)n * 128;
    s16x8 wf[4];
#pragma unroll
    for (int ks = 0; ks < 4; ++ks) wf[ks] = load8_f32(wr + ks * 32 + quad * 8);
    f32x4 acc[4];
#pragma unroll
    for (int mt = 0; mt < 4; ++mt) acc[mt] = (f32x4){0.f, 0.f, 0.f, 0.f};
#pragma unroll
    for (int mt = 0; mt < 4; ++mt)
#pragma unroll
      for (int ks = 0; ks < 4; ++ks)
        acc[mt] = __builtin_amdgcn_mfma_f32_16x16x32_bf16(af[mt][ks], wf[ks], acc[mt], 0, 0, 0);
    const float bv_ = bo[n];
#pragma unroll
    for (int mt = 0; mt < 4; ++mt)
#pragma unroll
      for (int r = 0; r < 4; ++r)
        Bt[mt * 16 + quad * 4 + r][n] = f2bf(acc[mt][r] + bv_);
  }
  __syncthreads();

  s16x8 a1[4][4], a2[4][4];
#pragma unroll
  for (int mt = 0; mt < 4; ++mt) {
#pragma unroll
    for (int ks = 0; ks < 4; ++ks)
      a1[mt][ks] = *(const s16x8*)&Bt[mt * 16 + l15][ks * 32 + quad * 8];
    const float* vrow = vae2 + (size_t)(grow0 + mt * 16 + l15) * 128;
#pragma unroll
    for (int ks = 0; ks < 4; ++ks) a2[mt][ks] = load8_f32(vrow + ks * 32 + quad * 8);
  }

#pragma unroll
  for (int nt = 0; nt < 2; ++nt) {
    const int n = (w * 2 + nt) * 16 + l15;
    const float* wr = Wf + (size_t)n * 256;
    s16x8 wfl[4], wfr[4];
#pragma unroll
    for (int ks = 0; ks < 4; ++ks) {
      wfl[ks] = load8_f32(wr + ks * 32 + quad * 8);
      wfr[ks] = load8_f32(wr + 128 + ks * 32 + quad * 8);
    }
    f32x4 acc[4];
#pragma unroll
    for (int mt = 0; mt < 4; ++mt) acc[mt] = (f32x4){0.f, 0.f, 0.f, 0.f};
#pragma unroll
    for (int mt = 0; mt < 4; ++mt) {
#pragma unroll
      for (int ks = 0; ks < 4; ++ks)
        acc[mt] = __builtin_amdgcn_mfma_f32_16x16x32_bf16(a1[mt][ks], wfl[ks], acc[mt], 0, 0, 0);
#pragma unroll
      for (int ks = 0; ks < 4; ++ks)
        acc[mt] = __builtin_amdgcn_mfma_f32_16x16x32_bf16(a2[mt][ks], wfr[ks], acc[mt], 0, 0, 0);
    }
    const float bv_ = bff[n];
#pragma unroll
    for (int mt = 0; mt < 4; ++mt)
#pragma unroll
      for (int r = 0; r < 4; ++r)
        out[(size_t)(grow0 + mt * 16 + quad * 4 + r) * 128 + n] = acc[mt][r] + bv_;
  }
}

extern "C" void kernel_launch(void* const* d_in, const int* in_sizes, int n_in,
                              void* d_out, int out_size, void* d_ws, size_t ws_size,
                              hipStream_t stream)
{
  const float* h    = (const float*)d_in[0];
  const float* adj  = (const float*)d_in[1];
  const float* vae2 = (const float*)d_in[2];
  const float* Wv1  = (const float*)d_in[3];
  const float* bv1  = (const float*)d_in[4];
  const float* Wk1  = (const float*)d_in[5];
  const float* bk1  = (const float*)d_in[6];
  const float* Wq1  = (const float*)d_in[7];
  const float* bq1  = (const float*)d_in[8];
  const float* Wo1  = (const float*)d_in[9];
  const float* bo1  = (const float*)d_in[10];
  const float* Wv2  = (const float*)d_in[11];
  const float* bv2  = (const float*)d_in[12];
  const float* Wk2  = (const float*)d_in[13];
  const float* bk2  = (const float*)d_in[14];
  const float* Wq2  = (const float*)d_in[15];
  const float* bq2  = (const float*)d_in[16];
  const float* Wo2  = (const float*)d_in[17];
  const float* bo2  = (const float*)d_in[18];
  const float* Wf   = (const float*)d_in[19];
  const float* bff  = (const float*)d_in[20];

  char* wsb = (char*)d_ws;
  const size_t MB = 1u << 20;
  unsigned short* s_q  = (unsigned short*)(wsb + 0 * MB);
  unsigned short* s_k  = (unsigned short*)(wsb + 4 * MB);
  unsigned short* s_vt = (unsigned short*)(wsb + 8 * MB);
  unsigned long long* maskp = (unsigned long long*)(wsb + 12 * MB);  // 4 MB
  float* pO = (float*)(wsb + 16 * MB);                               // 32 MB
  float* pl = (float*)(wsb + 48 * MB);                               // 256 KB

  qkv1_kernel<<<dim3(1024, 3), dim3(256), 0, stream>>>(
      h, Wq1, bq1, s_q, Wk1, bk1, s_k, Wv1, bv1, s_vt, adj, maskp);
  attn_kernel<<<dim3(128, NSPLIT), dim3(256), 0, stream>>>(
      s_q, s_k, s_vt, maskp, pO, pl);
  redqkv_kernel<<<dim3(256), dim3(256), 0, stream>>>(
      pO, pl, Wo1, bo1, Wq2, bq2, s_q, Wk2, bk2, s_k, Wv2, bv2, s_vt);
  attn_kernel<<<dim3(128, NSPLIT), dim3(256), 0, stream>>>(
      s_q, s_k, s_vt, maskp, pO, pl);
  redfinal_kernel<<<dim3(256), dim3(256), 0, stream>>>(
      pO, pl, Wo2, bo2, Wf, bff, vae2, (float*)d_out);
}